// Round 5
// baseline (339.383 us; speedup 1.0000x reference)
//
#include <hip/hip_runtime.h>
#include <hip/hip_bf16.h>

#define TEMP_INV 20.0f
#define BATCH    1024
#define NSAMP    100000
#define NFEAT    256
#define BM       128
#define BN       128
#define BK       64
#define NCH      782                 /* 782*128 = 100096 padded fb rows */

typedef __bf16 bf16x8 __attribute__((ext_vector_type(8)));
typedef float  f32x4  __attribute__((ext_vector_type(4)));

// async global->LDS, 16B per lane; LDS dest = wave-uniform base + lane*16
#define GLOAD_LDS16(g, l) __builtin_amdgcn_global_load_lds(               \
    (const __attribute__((address_space(1))) void*)(g),                   \
    (__attribute__((address_space(3))) void*)(l), 16, 0, 0)

#define WAITV(N) asm volatile("s_waitcnt vmcnt(" #N ")" ::: "memory")

// ---------------------------------------------------------------------------
// Kernel 0: convert feats (+zero-pad to 100096 rows) and inputs to bf16,
// zero-init out, AND (blocks 3160..3415) the per-row target-logit/shift work.
// ---------------------------------------------------------------------------
__global__ __launch_bounds__(256) void convert_target_kernel(
    const float* __restrict__ feats, const float* __restrict__ inputs,
    const int* __restrict__ targets, __bf16* __restrict__ fb,
    __bf16* __restrict__ ib, float* __restrict__ tlogit,
    float* __restrict__ mrow, float* __restrict__ out)
{
    if (blockIdx.x == 0 && threadIdx.x == 0) out[0] = 0.0f;
    int b = blockIdx.x;
    if (b < 3125) {
        size_t u0 = (size_t)b * 1024 + threadIdx.x;
        #pragma unroll
        for (int i = 0; i < 4; i++) {
            size_t u = u0 + (size_t)i * 256;
            const float4* src = (const float4*)(feats + u * 8);
            float4 a = src[0], c = src[1];
            bf16x8 o;
            o[0] = (__bf16)a.x; o[1] = (__bf16)a.y; o[2] = (__bf16)a.z; o[3] = (__bf16)a.w;
            o[4] = (__bf16)c.x; o[5] = (__bf16)c.y; o[6] = (__bf16)c.z; o[7] = (__bf16)c.w;
            *(bf16x8*)(fb + u * 8) = o;
        }
    } else if (b < 3128) {
        size_t u0 = 3200000 + (size_t)(b - 3125) * 1024 + threadIdx.x;
        bf16x8 z;
        #pragma unroll
        for (int q = 0; q < 8; q++) z[q] = (__bf16)0.0f;
        #pragma unroll
        for (int i = 0; i < 4; i++) {
            size_t u = u0 + (size_t)i * 256;
            if (u < 3203072) *(bf16x8*)(fb + u * 8) = z;
        }
    } else if (b < 3160) {
        size_t u0 = (size_t)(b - 3128) * 1024 + threadIdx.x;
        #pragma unroll
        for (int i = 0; i < 4; i++) {
            size_t u = u0 + (size_t)i * 256;
            const float4* src = (const float4*)(inputs + u * 8);
            float4 a = src[0], c = src[1];
            bf16x8 o;
            o[0] = (__bf16)a.x; o[1] = (__bf16)a.y; o[2] = (__bf16)a.z; o[3] = (__bf16)a.w;
            o[4] = (__bf16)c.x; o[5] = (__bf16)c.y; o[6] = (__bf16)c.z; o[7] = (__bf16)c.w;
            *(bf16x8*)(ib + u * 8) = o;
        }
    } else {
        // target work: 256 blocks x 4 rows; m_row = 5.4*||x|| (Gumbel-mode
        // max-logit estimate; exponents in [-30,+40] -> f32-safe).
        int lane = threadIdx.x & 63;
        int wid  = threadIdx.x >> 6;
        int row  = (b - 3160) * 4 + wid;
        int tgt  = targets[row];
        const float4* a = (const float4*)(inputs + (size_t)row * NFEAT);
        const float4* f = (const float4*)(feats  + (size_t)tgt * NFEAT);
        float4 av = a[lane];
        float4 fv = f[lane];
        float d  = av.x * fv.x + av.y * fv.y + av.z * fv.z + av.w * fv.w;
        float n2 = av.x * av.x + av.y * av.y + av.z * av.z + av.w * av.w;
        #pragma unroll
        for (int off = 1; off < 64; off <<= 1) {
            d  += __shfl_xor(d, off, 64);
            n2 += __shfl_xor(n2, off, 64);
        }
        if (lane == 0) {
            tlogit[row] = d * TEMP_INV;
            mrow[row]   = 5.4f * sqrtf(n2);
        }
    }
}

// ---------------------------------------------------------------------------
// Kernel 2: MFMA GEMM + fixed-shift exp-sum epilogue.
// 128x128 tile, BK=64, 4 waves (2wm x 2wn), wave-tile 64x64, acc[4][4].
// A: loaded ONCE into registers as MFMA fragments (areg[4][8], 128 VGPR) --
//    no A staging or A ds_reads in the loop.
// B: 2-slot LDS ring, distance-1 prefetch, counted vmcnt(4) (vmcnt(0) only
//    last iter).  Per iter: 4 gload_lds + 8 ds_read_b128 + 32 MFMA / wave.
// Grid 8mx x 782ny, XCD-clustered (mx fastest within an XCD's chunk).
// ~230 VGPR -> 2 blocks/CU; LDS 33 KB.
// ---------------------------------------------------------------------------
__global__ __launch_bounds__(256, 2) void gemm_softmax_kernel(
    const __bf16* __restrict__ A, const __bf16* __restrict__ B,
    const float* __restrict__ mrow, float* __restrict__ partials)
{
    int L  = blockIdx.x;
    int g  = (L & 7) * NCH + (L >> 3);   // bijective: 6256 = 8*782
    int mx = g & 7;
    int ny = g >> 3;
    int m0 = mx * BM;
    int n0 = ny * BN;

    __shared__ __bf16 Bbuf[2][BN][BK];   // 2 x 16 KB
    __shared__ float  red[2][BM];        // 1 KB

    const int tid    = threadIdx.x;
    const int lane   = tid & 63;
    const int wid    = tid >> 6;
    const int wm     = wid & 1;
    const int wn     = wid >> 1;
    const int lrow   = lane & 15;
    const int quad   = lane >> 4;
    const int rowoff = lane >> 3;            // 0..7
    const int kc     = (lane & 7) ^ rowoff;  // pre-swizzled k-chunk (0-conflict)

    const __bf16* Bg = B + (size_t)(n0 + wid * 32 + rowoff) * NFEAT + kc * 8;

#define STAGE(KT, SLOT) do {                                                  \
    _Pragma("unroll")                                                         \
    for (int i2 = 0; i2 < 4; i2++)                                            \
        GLOAD_LDS16(Bg + (KT) * BK + (size_t)(i2 * 8) * NFEAT,                \
                    &Bbuf[SLOT][wid * 32 + i2 * 8][0]);                       \
  } while (0)

    // ---- prologue: B(0) -> slot0; A fragments -> registers ----
    STAGE(0, 0);

    // A fragment layout for mfma_16x16x32: lane reads row (wm*64+mi*16+lrow),
    // k-chunk (kt*32 + quad*8), 16 B each -> rows in 64B spans, L2-friendly.
    bf16x8 areg[4][8];                     // 128 VGPR
    {
        const __bf16* Arow = A + (size_t)(m0 + wm * 64 + lrow) * NFEAT + quad * 8;
        #pragma unroll
        for (int mi = 0; mi < 4; mi++)
            #pragma unroll
            for (int kt = 0; kt < 8; kt++)
                areg[mi][kt] = *(const bf16x8*)(Arow + (size_t)(mi * 16) * NFEAT + kt * 32);
    }

    f32x4 acc[4][4] = {};

    #pragma unroll
    for (int it = 0; it < 4; it++) {
        __builtin_amdgcn_s_barrier();     // all waves done reading buf[(it+1)&1]
        if (it < 3) {
            STAGE(it + 1, (it + 1) & 1);
            WAITV(4);                     // stage(it) complete; stage(it+1) in flight
        } else {
            WAITV(0);
        }
        __builtin_amdgcn_sched_barrier(0);
        __builtin_amdgcn_s_barrier();     // staged data visible block-wide

        #pragma unroll
        for (int ks = 0; ks < 2; ks++) {
            bf16x8 bfr[4];
            #pragma unroll
            for (int ni = 0; ni < 4; ni++) {
                int R = wn * 64 + ni * 16 + lrow;
                bfr[ni] = *(const bf16x8*)&Bbuf[it & 1][R][((ks * 4 + quad) ^ (R & 7)) * 8];
            }
            #pragma unroll
            for (int mi = 0; mi < 4; mi++)
                #pragma unroll
                for (int ni = 0; ni < 4; ni++)
                    acc[mi][ni] = __builtin_amdgcn_mfma_f32_16x16x32_bf16(
                        areg[mi][it * 2 + ks], bfr[ni], acc[mi][ni], 0, 0, 0);
        }
    }
#undef STAGE

    // ---- epilogue: s = sum_cols exp(20*acc - m_row), plain add reduce ----
    // C layout per 16x16 tile: row = quad*4 + reg, col = lane&15
    #pragma unroll
    for (int mi = 0; mi < 4; mi++) {
        #pragma unroll
        for (int reg = 0; reg < 4; reg++) {
            float mrv = mrow[m0 + wm * 64 + mi * 16 + quad * 4 + reg];
            float s = __expf(acc[mi][0][reg] * TEMP_INV - mrv)
                    + __expf(acc[mi][1][reg] * TEMP_INV - mrv)
                    + __expf(acc[mi][2][reg] * TEMP_INV - mrv)
                    + __expf(acc[mi][3][reg] * TEMP_INV - mrv);
            #pragma unroll
            for (int off = 1; off < 16; off <<= 1)
                s += __shfl_xor(s, off, 64);
            if (lrow == 0)
                red[wn][wm * 64 + mi * 16 + quad * 4 + reg] = s;
        }
    }
    __syncthreads();
    if (tid < BM)
        partials[(size_t)ny * BATCH + (m0 + tid)] = red[0][tid] + red[1][tid];
}

// ---------------------------------------------------------------------------
// Kernel 3: sum partials -> lse = m_row + log(S) -> nll -> mean (atomicAdd).
// ---------------------------------------------------------------------------
__global__ __launch_bounds__(256) void reduce_kernel(
    const float* __restrict__ partials, const float* __restrict__ tlogit,
    const float* __restrict__ mrow, float* __restrict__ out)
{
    __shared__ float red2[8][32];
    int tid = threadIdx.x;
    int rl  = tid & 31;
    int sp  = tid >> 5;
    int row = blockIdx.x * 32 + rl;
    int cs  = sp * 98;
    int ce  = cs + 98 < NCH ? cs + 98 : NCH;
    float s = 0.f;
    #pragma unroll 4
    for (int c = cs; c < ce; c++)
        s += partials[(size_t)c * BATCH + row];
    red2[sp][rl] = s;
    __syncthreads();
    if (tid < 32) {
        float S = 0.f;
        #pragma unroll
        for (int q = 0; q < 8; q++) S += red2[q][rl];
        float nll = (mrow[row] + logf(S)) - tlogit[row];
        #pragma unroll
        for (int off = 1; off < 32; off <<= 1)
            nll += __shfl_xor(nll, off, 64);
        if (rl == 0) atomicAdd(out, nll * (1.0f / BATCH));
    }
}

// ---------------------------------------------------------------------------
extern "C" void kernel_launch(void* const* d_in, const int* in_sizes, int n_in,
                              void* d_out, int out_size, void* d_ws, size_t ws_size,
                              hipStream_t stream) {
    const float* inputs  = (const float*)d_in[0];
    const int*   targets = (const int*)d_in[1];
    const float* feats   = (const float*)d_in[2];
    float* out = (float*)d_out;

    // ws layout (bytes):
    //   fb       : 0          .. 51,249,152   (100096*256 bf16)
    //   ib       : 51,249,152 .. 51,773,440   (1024*256 bf16)
    //   partials : 51,773,440 .. 54,976,512   (782*1024 f32)
    //   tlogit   : 54,976,512 .. +4096
    //   mrow     : 54,980,608 .. +4096
    __bf16* fb       = (__bf16*)d_ws;
    __bf16* ib       = (__bf16*)((char*)d_ws + 51249152);
    float*  partials = (float*)((char*)d_ws + 51773440);
    float*  tlogit   = (float*)((char*)d_ws + 54976512);
    float*  mrow     = (float*)((char*)d_ws + 54980608);

    convert_target_kernel<<<3416, 256, 0, stream>>>(feats, inputs, targets,
                                                    fb, ib, tlogit, mrow, out);
    gemm_softmax_kernel<<<8 * NCH, 256, 0, stream>>>(ib, fb, mrow, partials);
    reduce_kernel<<<BATCH / 32, 256, 0, stream>>>(partials, tlogit, mrow, out);
}

// Round 6
// 281.568 us; speedup vs baseline: 1.2053x; 1.2053x over previous
//
#include <hip/hip_runtime.h>
#include <hip/hip_bf16.h>

#define TEMP_INV 20.0f
#define BATCH    1024
#define NSAMP    100000
#define NFEAT    256
#define NCH      391                 /* n-chunks of 256: 391*256 = 100096 */

typedef __bf16 bf16x8 __attribute__((ext_vector_type(8)));
typedef float  f32x4  __attribute__((ext_vector_type(4)));

// async global->LDS, 16B per lane; LDS dest = wave-uniform base + lane*16
#define GLOAD_LDS16(g, l) __builtin_amdgcn_global_load_lds(               \
    (const __attribute__((address_space(1))) void*)(g),                   \
    (__attribute__((address_space(3))) void*)(l), 16, 0, 0)

// ---------------------------------------------------------------------------
// Kernel 0: convert feats (+zero-pad to 100096 rows) and inputs to bf16,
// zero-init out + partials, AND (blocks 3160..3415) per-row target logit /
// softmax shift.  m_row = 5.4*||x|| (Gumbel-mode max-logit estimate;
// exponents stay in [-30,+40] -> f32-safe fixed shift).
// ---------------------------------------------------------------------------
__global__ __launch_bounds__(256) void convert_target_kernel(
    const float* __restrict__ feats, const float* __restrict__ inputs,
    const int* __restrict__ targets, __bf16* __restrict__ fb,
    __bf16* __restrict__ ib, float* __restrict__ tlogit,
    float* __restrict__ mrow, float* __restrict__ partials,
    float* __restrict__ out)
{
    if (blockIdx.x == 0 && threadIdx.x == 0) out[0] = 0.0f;
    int b = blockIdx.x;
    if (b < 3125) {
        size_t u0 = (size_t)b * 1024 + threadIdx.x;
        #pragma unroll
        for (int i = 0; i < 4; i++) {
            size_t u = u0 + (size_t)i * 256;
            const float4* src = (const float4*)(feats + u * 8);
            float4 a = src[0], c = src[1];
            bf16x8 o;
            o[0] = (__bf16)a.x; o[1] = (__bf16)a.y; o[2] = (__bf16)a.z; o[3] = (__bf16)a.w;
            o[4] = (__bf16)c.x; o[5] = (__bf16)c.y; o[6] = (__bf16)c.z; o[7] = (__bf16)c.w;
            *(bf16x8*)(fb + u * 8) = o;
        }
    } else if (b < 3128) {
        size_t u0 = 3200000 + (size_t)(b - 3125) * 1024 + threadIdx.x;
        bf16x8 z;
        #pragma unroll
        for (int q = 0; q < 8; q++) z[q] = (__bf16)0.0f;
        #pragma unroll
        for (int i = 0; i < 4; i++) {
            size_t u = u0 + (size_t)i * 256;
            if (u < 3203072) *(bf16x8*)(fb + u * 8) = z;
        }
    } else if (b < 3160) {
        size_t u0 = (size_t)(b - 3128) * 1024 + threadIdx.x;
        #pragma unroll
        for (int i = 0; i < 4; i++) {
            size_t u = u0 + (size_t)i * 256;
            const float4* src = (const float4*)(inputs + u * 8);
            float4 a = src[0], c = src[1];
            bf16x8 o;
            o[0] = (__bf16)a.x; o[1] = (__bf16)a.y; o[2] = (__bf16)a.z; o[3] = (__bf16)a.w;
            o[4] = (__bf16)c.x; o[5] = (__bf16)c.y; o[6] = (__bf16)c.z; o[7] = (__bf16)c.w;
            *(bf16x8*)(ib + u * 8) = o;
        }
    } else if (b < 3416) {
        int lane = threadIdx.x & 63;
        int wid  = threadIdx.x >> 6;
        int row  = (b - 3160) * 4 + wid;
        int tgt  = targets[row];
        const float4* a = (const float4*)(inputs + (size_t)row * NFEAT);
        const float4* f = (const float4*)(feats  + (size_t)tgt * NFEAT);
        float4 av = a[lane];
        float4 fv = f[lane];
        float d  = av.x * fv.x + av.y * fv.y + av.z * fv.z + av.w * fv.w;
        float n2 = av.x * av.x + av.y * av.y + av.z * av.z + av.w * av.w;
        #pragma unroll
        for (int off = 1; off < 64; off <<= 1) {
            d  += __shfl_xor(d, off, 64);
            n2 += __shfl_xor(n2, off, 64);
        }
        if (lane == 0) {
            tlogit[row] = d * TEMP_INV;
            mrow[row]   = 5.4f * sqrtf(n2);
        }
    } else {
        // zero partials[1024]
        float4 z = {0.f, 0.f, 0.f, 0.f};
        ((float4*)partials)[threadIdx.x] = z;
    }
}

// ---------------------------------------------------------------------------
// Kernel 2: MFMA GEMM + fixed-shift exp-sum epilogue, BARRIER-FREE K-loop.
// Tile 64x256, 4 waves split along N only (wave-tile 64x64) -> no operand
// duplication.  A (64x256, 32KB) staged into XOR-swizzled LDS ONCE
// (pre-swizzled global source, linear LDS dest); shared read-only by all
// waves.  B fragments loaded DIRECTLY global->VGPR per kt: wave reads 16
// consecutive rows x 64 contiguous bytes per (ni,kt) -> fully line-
// efficient, each B byte read once per block.  No barriers / waitcnt in
// the loop: 12 resident waves free-run and overlap loads with MFMA.
// Per-block exp-sums accumulated into partials[1024] via atomicAdd.
// Grid 16mx x 391ny, XCD-clustered (mx fastest within an XCD's g-range).
// ---------------------------------------------------------------------------
__global__ __launch_bounds__(256, 3) void gemm_softmax_kernel(
    const __bf16* __restrict__ A, const __bf16* __restrict__ B,
    const float* __restrict__ mrow, float* __restrict__ partials)
{
    int L  = blockIdx.x;
    int g  = (L & 7) * 782 + (L >> 3);   // bijective: 6256 = 8*782
    int mx = g & 15;
    int ny = g >> 4;
    int m0 = mx * 64;
    int n0 = ny * 256;

    __shared__ __bf16 Alds[64][256];     // 32 KB, chunk-swizzled c^(row&7)
    __shared__ float  red[4][64];        // 1 KB

    const int tid  = threadIdx.x;
    const int lane = tid & 63;
    const int wid  = tid >> 6;           // = wn (N-split only)
    const int lrow = lane & 15;
    const int quad = lane >> 4;

    // ---- stage A once: wave wid stages rows [wid*16, wid*16+16) ----
    // gload_lds dest is linear: lane l -> row +(l>>5), chunk l&31.
    // Swizzled layout via pre-swizzled SOURCE: slot (r, c) holds global
    // chunk c ^ (r&7).
    {
        const int r2 = lane >> 5;        // 0..1
        const int cl = lane & 31;
        const __bf16* Ag0 = A + (size_t)(m0 + wid * 16 + r2) * NFEAT;
        #pragma unroll
        for (int i = 0; i < 8; i++) {
            const __bf16* src = Ag0 + (size_t)(2 * i) * NFEAT
                                + ((cl ^ ((2 * i + r2) & 7)) * 8);
            GLOAD_LDS16(src, &Alds[wid * 16 + 2 * i][0]);
        }
    }
    asm volatile("s_waitcnt vmcnt(0)" ::: "memory");
    __builtin_amdgcn_s_barrier();

    // ---- barrier-free K-loop ----
    const __bf16* Bg = B + (size_t)(n0 + wid * 64 + lrow) * NFEAT + quad * 8;
    f32x4 acc[4][4] = {};

    #pragma unroll 2
    for (int kt = 0; kt < 8; kt++) {
        bf16x8 bfr[4], af[4];
        #pragma unroll
        for (int ni = 0; ni < 4; ni++)
            bfr[ni] = *(const bf16x8*)(Bg + (size_t)(ni * 16) * NFEAT + kt * 32);
        #pragma unroll
        for (int mi = 0; mi < 4; mi++) {
            int R = mi * 16 + lrow;
            af[mi] = *(const bf16x8*)&Alds[R][((kt * 4 + quad) ^ (R & 7)) * 8];
        }
        #pragma unroll
        for (int mi = 0; mi < 4; mi++)
            #pragma unroll
            for (int ni = 0; ni < 4; ni++)
                acc[mi][ni] = __builtin_amdgcn_mfma_f32_16x16x32_bf16(
                    af[mi], bfr[ni], acc[mi][ni], 0, 0, 0);
    }

    // ---- epilogue: s = sum_cols exp(20*acc - m_row) ----
    // C layout per 16x16 tile: row = quad*4 + reg (A rows), col = lane&15
    // (B rows).  Padded fb rows give exp(-m_row) ~ 0.
    #pragma unroll
    for (int mi = 0; mi < 4; mi++) {
        #pragma unroll
        for (int reg = 0; reg < 4; reg++) {
            float mrv = mrow[m0 + mi * 16 + quad * 4 + reg];
            float s = __expf(acc[mi][0][reg] * TEMP_INV - mrv)
                    + __expf(acc[mi][1][reg] * TEMP_INV - mrv)
                    + __expf(acc[mi][2][reg] * TEMP_INV - mrv)
                    + __expf(acc[mi][3][reg] * TEMP_INV - mrv);
            #pragma unroll
            for (int off = 1; off < 16; off <<= 1)
                s += __shfl_xor(s, off, 64);
            if (lrow == 0)
                red[wid][mi * 16 + quad * 4 + reg] = s;
        }
    }
    __syncthreads();
    if (tid < 64)
        atomicAdd(&partials[m0 + tid],
                  red[0][tid] + red[1][tid] + red[2][tid] + red[3][tid]);
}

// ---------------------------------------------------------------------------
// Kernel 3: lse = m_row + log(S) -> nll -> mean (atomicAdd).  4 blocks.
// ---------------------------------------------------------------------------
__global__ __launch_bounds__(256) void reduce_kernel(
    const float* __restrict__ partials, const float* __restrict__ tlogit,
    const float* __restrict__ mrow, float* __restrict__ out)
{
    __shared__ float red2[4];
    int tid = threadIdx.x;
    int row = blockIdx.x * 256 + tid;
    float nll = (mrow[row] + logf(partials[row])) - tlogit[row];
    #pragma unroll
    for (int off = 1; off < 64; off <<= 1)
        nll += __shfl_xor(nll, off, 64);
    if ((tid & 63) == 0) red2[tid >> 6] = nll;
    __syncthreads();
    if (tid == 0)
        atomicAdd(out, (red2[0] + red2[1] + red2[2] + red2[3]) * (1.0f / BATCH));
}

// ---------------------------------------------------------------------------
extern "C" void kernel_launch(void* const* d_in, const int* in_sizes, int n_in,
                              void* d_out, int out_size, void* d_ws, size_t ws_size,
                              hipStream_t stream) {
    const float* inputs  = (const float*)d_in[0];
    const int*   targets = (const int*)d_in[1];
    const float* feats   = (const float*)d_in[2];
    float* out = (float*)d_out;

    // ws layout (bytes):
    //   fb       : 0          .. 51,249,152   (100096*256 bf16)
    //   ib       : 51,249,152 .. 51,773,440   (1024*256 bf16)
    //   partials : 51,773,440 .. +4096        (1024 f32)
    //   tlogit   : 51,777,536 .. +4096
    //   mrow     : 51,781,632 .. +4096
    __bf16* fb       = (__bf16*)d_ws;
    __bf16* ib       = (__bf16*)((char*)d_ws + 51249152);
    float*  partials = (float*)((char*)d_ws + 51773440);
    float*  tlogit   = (float*)((char*)d_ws + 51777536);
    float*  mrow     = (float*)((char*)d_ws + 51781632);

    convert_target_kernel<<<3417, 256, 0, stream>>>(feats, inputs, targets,
                                                    fb, ib, tlogit, mrow,
                                                    partials, out);
    gemm_softmax_kernel<<<6256, 256, 0, stream>>>(ib, fb, mrow, partials);
    reduce_kernel<<<4, 256, 0, stream>>>(partials, tlogit, mrow, out);
}